// Round 8
// baseline (49742.685 us; speedup 1.0000x reference)
//
#include <hip/hip_runtime.h>
#include <math.h>

#define B_   64
#define S_   512
#define IN_  512
#define H_   1024
#define WLK_ (H_ + 128)
#define NBLK 256
#define NTHR 512

typedef unsigned long long ull;
typedef float    f32x4 __attribute__((ext_vector_type(4)));
typedef unsigned u32x4 __attribute__((ext_vector_type(4)));

// ---- static device scratch ----
__device__ float g_xT[(size_t)S_ * IN_ * B_];   // [s][k][b]
__device__ float g_h0T[H_ * B_];                // [k][b]
__device__ float g_hT[2][H_ * B_];              // [k][b]
__device__ float g_hhatT[H_ * B_];              // [j][b]
__device__ float g_zprojT[H_ * B_];             // [j][b] includes b_lin
__device__ unsigned g_bar[2 * S_][256];         // 8 live counters/slot, 128B apart

// SRD for buffer_load: base, bounds disabled, raw dword
__device__ __forceinline__ u32x4 make_srd(const void* p) {
    ull a = (ull)p;
    u32x4 r;
    r.x = (unsigned)a; r.y = (unsigned)(a >> 32);
    r.z = 0xFFFFFFFFu;            // num_records: bounds check disabled
    r.w = 0x00020000u;            // raw untyped dword
    return r;
}

__device__ __forceinline__ void coh_store2(float* p, float x, float y) {
    union { float2 f; ull u; } v; v.f = make_float2(x, y);
    __hip_atomic_store((ull*)p, v.u, __ATOMIC_RELAXED, __HIP_MEMORY_SCOPE_AGENT);
}

// 8 device-coherent (sc1) 16B loads; voff advances 0x2000 (=32 k-rows) each.
#define ISSUE8(d0,d1,d2,d3,d4,d5,d6,d7, off, rs) \
  asm volatile( \
    "buffer_load_dwordx4 %0, %8, %9, 0 offen sc1\n\t" \
    "v_add_u32 %8, 0x2000, %8\n\t" \
    "buffer_load_dwordx4 %1, %8, %9, 0 offen sc1\n\t" \
    "v_add_u32 %8, 0x2000, %8\n\t" \
    "buffer_load_dwordx4 %2, %8, %9, 0 offen sc1\n\t" \
    "v_add_u32 %8, 0x2000, %8\n\t" \
    "buffer_load_dwordx4 %3, %8, %9, 0 offen sc1\n\t" \
    "v_add_u32 %8, 0x2000, %8\n\t" \
    "buffer_load_dwordx4 %4, %8, %9, 0 offen sc1\n\t" \
    "v_add_u32 %8, 0x2000, %8\n\t" \
    "buffer_load_dwordx4 %5, %8, %9, 0 offen sc1\n\t" \
    "v_add_u32 %8, 0x2000, %8\n\t" \
    "buffer_load_dwordx4 %6, %8, %9, 0 offen sc1\n\t" \
    "v_add_u32 %8, 0x2000, %8\n\t" \
    "buffer_load_dwordx4 %7, %8, %9, 0 offen sc1\n\t" \
    "v_add_u32 %8, 0x2000, %8\n\t" \
    : "=v"(d0),"=v"(d1),"=v"(d2),"=v"(d3),"=v"(d4),"=v"(d5),"=v"(d6),"=v"(d7),"+v"(off) \
    : "s"(rs) : "memory")

#define WAITV(n) do { asm volatile("s_waitcnt vmcnt(" #n ")" ::: "memory"); \
                      __builtin_amdgcn_sched_barrier(0); } while (0)

#define F4(AC, WS) AC.x=fmaf(WS,a.x,AC.x); AC.y=fmaf(WS,a.y,AC.y); AC.z=fmaf(WS,a.z,AC.z); AC.w=fmaf(WS,a.w,AC.w);

// ---------------- prologue 1: transpose inputs [B][S][IN] -> xT [S][IN][B] ----
__global__ void pre_transpose_x(const float* __restrict__ in) {
    __shared__ float lds[64][65];
    int s  = blockIdx.x >> 3;
    int k0 = (blockIdx.x & 7) << 6;
    int tid = threadIdx.x;
    int kk = tid & 63, bq = tid >> 6;
    for (int b = bq; b < 64; b += 4)
        lds[kk][b] = in[((size_t)b * S_ + s) * IN_ + k0 + kk];
    __syncthreads();
    int bb = tid & 63, kq = tid >> 6;
    for (int k = kq; k < 64; k += 4)
        g_xT[((size_t)s * IN_ + k0 + k) * B_ + bb] = lds[k][bb];
}

// ---------------- prologue 2: z_projT (incl b_lin), h0T, zero barriers ------
__global__ void pre_misc(const float* __restrict__ z, const float* __restrict__ Wlin,
                         const float* __restrict__ blin, const float* __restrict__ h0) {
    __shared__ float zT[128][65];
    int j = blockIdx.x;      // 0..1023
    int b = threadIdx.x;     // 0..63
    for (int i = 0; i < 128; ++i) {
        int idx = b + (i << 6);
        zT[idx & 127][idx >> 7] = z[idx];
    }
    __syncthreads();
    float acc = blin[j];
    const float* w = Wlin + (size_t)j * WLK_ + H_;
    for (int k = 0; k < 128; ++k)
        acc = fmaf(zT[k][b], w[k], acc);
    g_zprojT[j * 64 + b] = acc;
    g_h0T[j * 64 + b]    = h0[(size_t)b * H_ + j];
    for (int i = b; i < 256; i += 64)
        g_bar[j][i] = 0;
}

// 12-col GEMM over K=512, NORMAL cached loads (x is read-only) — unchanged R7
__device__ __forceinline__ void gemm12n(const float* __restrict__ src,
                                        const float* wl,
                                        const float* bias_l, float* dst,
                                        float* red, int tid) {
    const int bq = tid & 15, kq = tid >> 4;
    const int wv = tid >> 6, ln = tid & 63;
    const float* ap = src + (kq << 6) + (bq << 2);
    const float* wp = wl + kq * 12;
    f32x4 acc[12];
    #pragma unroll
    for (int c = 0; c < 12; ++c) acc[c] = (f32x4){0.f,0.f,0.f,0.f};
    #pragma unroll 4
    for (int i = 0; i < 16; ++i) {
        f32x4 a  = *(const f32x4*)ap;  ap += 32 * 64;
        f32x4 w0 = *(const f32x4*)(wp + 0);
        f32x4 w1 = *(const f32x4*)(wp + 4);
        f32x4 w2 = *(const f32x4*)(wp + 8);  wp += 32 * 12;
        F4(acc[0],w0.x) F4(acc[1],w0.y) F4(acc[2],w0.z)  F4(acc[3],w0.w)
        F4(acc[4],w1.x) F4(acc[5],w1.y) F4(acc[6],w1.z)  F4(acc[7],w1.w)
        F4(acc[8],w2.x) F4(acc[9],w2.y) F4(acc[10],w2.z) F4(acc[11],w2.w)
    }
    #pragma unroll
    for (int c = 0; c < 12; ++c) {
        f32x4 v = acc[c];
        v.x += __shfl_xor(v.x,16); v.y += __shfl_xor(v.y,16);
        v.z += __shfl_xor(v.z,16); v.w += __shfl_xor(v.w,16);
        v.x += __shfl_xor(v.x,32); v.y += __shfl_xor(v.y,32);
        v.z += __shfl_xor(v.z,32); v.w += __shfl_xor(v.w,32);
        if (ln < 16) *(f32x4*)&red[(wv * 12 + c) * 64 + (ln << 2)] = v;
    }
    __syncthreads();
    for (int o = tid; o < 768; o += NTHR) {
        int c = o >> 6, b = o & 63;
        float s = bias_l[c];
        #pragma unroll
        for (int w = 0; w < 8; ++w) s += red[(w * 12 + c) * 64 + b];
        dst[o] = s;
    }
}

#define FMA12(AV) do { f32x4 a = (AV); \
    f32x4 w0 = *(const f32x4*)(wp); \
    f32x4 w1 = *(const f32x4*)(wp + 4); \
    f32x4 w2 = *(const f32x4*)(wp + 8); \
    wp += 32 * 12; \
    F4(c0,w0.x) F4(c1,w0.y) F4(c2,w0.z)  F4(c3,w0.w) \
    F4(c4,w1.x) F4(c5,w1.y) F4(c6,w1.z)  F4(c7,w1.w) \
    F4(c8,w2.x) F4(c9,w2.y) F4(c10,w2.z) F4(c11,w2.w) } while (0)

#define RED1(AC, cc, NC) { f32x4 v = AC; \
    v.x += __shfl_xor(v.x,16); v.y += __shfl_xor(v.y,16); \
    v.z += __shfl_xor(v.z,16); v.w += __shfl_xor(v.w,16); \
    v.x += __shfl_xor(v.x,32); v.y += __shfl_xor(v.y,32); \
    v.z += __shfl_xor(v.z,32); v.w += __shfl_xor(v.w,32); \
    if (ln < 16) *(f32x4*)&red[(wv * NC + cc) * 64 + (ln << 2)] = v; }

// 12-col GEMM over K=1024, DEVICE-COHERENT pipelined loads (h_hat)
__device__ __forceinline__ void gemm12c(const float* src, const float* wl,
                                        const float* bias_l, float* dst,
                                        float* red, int tid) {
    const int bq = tid & 15, kq = tid >> 4;
    const int wv = tid >> 6, ln = tid & 63;
    u32x4 rs = make_srd(src);
    unsigned voff = (unsigned)((((kq << 6) + (bq << 2))) << 2);
    const float* wp = wl + kq * 12;
    f32x4 c0={0,0,0,0},c1={0,0,0,0},c2={0,0,0,0},c3={0,0,0,0},c4={0,0,0,0},c5={0,0,0,0},
          c6={0,0,0,0},c7={0,0,0,0},c8={0,0,0,0},c9={0,0,0,0},c10={0,0,0,0},c11={0,0,0,0};
    f32x4 A0,A1,A2,A3,A4,A5,A6,A7, B0,B1,B2,B3,B4,B5,B6,B7;
    ISSUE8(A0,A1,A2,A3,A4,A5,A6,A7, voff, rs);
    ISSUE8(B0,B1,B2,B3,B4,B5,B6,B7, voff, rs);
    WAITV(8);
    FMA12(A0); FMA12(A1); FMA12(A2); FMA12(A3); FMA12(A4); FMA12(A5); FMA12(A6); FMA12(A7);
    ISSUE8(A0,A1,A2,A3,A4,A5,A6,A7, voff, rs);
    WAITV(8);
    FMA12(B0); FMA12(B1); FMA12(B2); FMA12(B3); FMA12(B4); FMA12(B5); FMA12(B6); FMA12(B7);
    ISSUE8(B0,B1,B2,B3,B4,B5,B6,B7, voff, rs);
    WAITV(8);
    FMA12(A0); FMA12(A1); FMA12(A2); FMA12(A3); FMA12(A4); FMA12(A5); FMA12(A6); FMA12(A7);
    WAITV(0);
    FMA12(B0); FMA12(B1); FMA12(B2); FMA12(B3); FMA12(B4); FMA12(B5); FMA12(B6); FMA12(B7);
    RED1(c0,0,12)  RED1(c1,1,12)  RED1(c2,2,12)   RED1(c3,3,12)
    RED1(c4,4,12)  RED1(c5,5,12)  RED1(c6,6,12)   RED1(c7,7,12)
    RED1(c8,8,12)  RED1(c9,9,12)  RED1(c10,10,12) RED1(c11,11,12)
    __syncthreads();
    for (int o = tid; o < 768; o += NTHR) {
        int c = o >> 6, b = o & 63;
        float s = bias_l[c];
        #pragma unroll
        for (int w = 0; w < 8; ++w) s += red[(w * 12 + c) * 64 + b];
        dst[o] = s;
    }
}

// ---------------- persistent recurrence kernel ------------------------------
__launch_bounds__(NTHR, 1)
__global__ void skipgru_2ph(const float* __restrict__ Wlin, const float* __restrict__ Wih,
                            const float* __restrict__ bih,  const float* __restrict__ Whh,
                            const float* __restrict__ bhh,  float* __restrict__ out) {
    __shared__ float wA[H_ * 4];        // 16 KB [k][c<4]
    __shared__ float wB[H_ * 12];       // 48 KB [k][c<12]
    __shared__ float wX[IN_ * 12];      // 24 KB [k][c<12]
    __shared__ float red[8 * 12 * 64];  // 24 KB
    __shared__ float gh_l[12 * 64];
    __shared__ float gi_a[12 * 64];
    __shared__ float gi_b[12 * 64];
    __shared__ float hh_l[4 * 64];
    __shared__ float hn_l[4 * 64];
    __shared__ float zp_l[4 * 64];
    __shared__ float bhh_l[12];
    __shared__ float bih_l[12];

    const int tid = threadIdx.x;
    const int jb  = blockIdx.x << 2;
    const int bq  = tid & 15;
    const int kq  = tid >> 4;
    const int wv  = tid >> 6, ln = tid & 63;
    const int barlane = (blockIdx.x & 7) << 5;

    for (int c = 0; c < 4; ++c) {
        const float* src = Wlin + (size_t)(jb + c) * WLK_;
        for (int k = tid; k < H_; k += NTHR) wA[k * 4 + c] = src[k];
    }
    for (int c = 0; c < 12; ++c) {
        const float* src = Whh + (size_t)((c >> 2) * H_ + jb + (c & 3)) * H_;
        for (int k = tid; k < H_; k += NTHR) wB[k * 12 + c] = src[k];
    }
    for (int c = 0; c < 12; ++c) {
        const float* src = Wih + (size_t)((c >> 2) * H_ + jb + (c & 3)) * IN_;
        for (int k = tid; k < IN_; k += NTHR) wX[k * 12 + c] = src[k];
    }
    if (tid < 256) zp_l[tid] = g_zprojT[(jb + (tid >> 6)) * 64 + (tid & 63)];
    if (tid < 12) {
        bhh_l[tid] = bhh[(tid >> 2) * H_ + jb + (tid & 3)];
        bih_l[tid] = bih[(tid >> 2) * H_ + jb + (tid & 3)];
    }
    __syncthreads();

    gemm12n(g_xT, wX, bih_l, gi_a, red, tid);
    __syncthreads();

    for (int t = 0; t < S_; ++t) {
        const float* hs = (t == 0) ? g_h0T : g_hT[t & 1];
        const float* gi_cur = (t & 1) ? gi_b : gi_a;
        float*       gi_nxt = (t & 1) ? gi_a : gi_b;

        // ---- P1: h_hat, 4 cols, K=1024, coherent pipelined loads ----
        {
            u32x4 rs = make_srd(hs);
            unsigned voff = (unsigned)((((kq << 6) + (bq << 2))) << 2);
            const float* wp = wA + kq * 4;
            f32x4 c0={0,0,0,0},c1={0,0,0,0},c2={0,0,0,0},c3={0,0,0,0};
            f32x4 A0,A1,A2,A3,A4,A5,A6,A7, B0,B1,B2,B3,B4,B5,B6,B7;
            #define FMA4(AV) do { f32x4 a = (AV); \
                f32x4 w = *(const f32x4*)wp;  wp += 32 * 4; \
                F4(c0,w.x) F4(c1,w.y) F4(c2,w.z) F4(c3,w.w) } while (0)
            ISSUE8(A0,A1,A2,A3,A4,A5,A6,A7, voff, rs);
            ISSUE8(B0,B1,B2,B3,B4,B5,B6,B7, voff, rs);
            WAITV(8);
            FMA4(A0); FMA4(A1); FMA4(A2); FMA4(A3); FMA4(A4); FMA4(A5); FMA4(A6); FMA4(A7);
            ISSUE8(A0,A1,A2,A3,A4,A5,A6,A7, voff, rs);
            WAITV(8);
            FMA4(B0); FMA4(B1); FMA4(B2); FMA4(B3); FMA4(B4); FMA4(B5); FMA4(B6); FMA4(B7);
            ISSUE8(B0,B1,B2,B3,B4,B5,B6,B7, voff, rs);
            WAITV(8);
            FMA4(A0); FMA4(A1); FMA4(A2); FMA4(A3); FMA4(A4); FMA4(A5); FMA4(A6); FMA4(A7);
            WAITV(0);
            FMA4(B0); FMA4(B1); FMA4(B2); FMA4(B3); FMA4(B4); FMA4(B5); FMA4(B6); FMA4(B7);
            #undef FMA4
            RED1(c0,0,4) RED1(c1,1,4) RED1(c2,2,4) RED1(c3,3,4)
        }
        __syncthreads();
        if (tid < 256) {
            int c = tid >> 6, b = tid & 63;
            float s = zp_l[tid];
            #pragma unroll
            for (int w = 0; w < 8; ++w) s += red[(w * 4 + c) * 64 + b];
            hh_l[tid] = s;
        }
        __syncthreads();
        if (tid < 128) {
            int c = tid >> 5, pb = (tid & 31) << 1;
            coh_store2(&g_hhatT[(jb + c) * 64 + pb], hh_l[(c << 6) + pb], hh_l[(c << 6) + pb + 1]);
        }
        __syncthreads();   // vmcnt(0) drain: h_hat stores complete before arrive

        // ---- arrive A ----
        if (tid == 0)
            __hip_atomic_fetch_add(&g_bar[2 * t][barlane], 1u, __ATOMIC_RELAXED, __HIP_MEMORY_SCOPE_AGENT);

        // ---- gi(t+1), hidden under barrier A ----
        if (t + 1 < S_)
            gemm12n(g_xT + (size_t)(t + 1) * IN_ * B_, wX, bih_l, gi_nxt, red, tid);

        // ---- wait A ----
        if (tid == 0) {
            unsigned s;
            do {
                s = 0;
                #pragma unroll
                for (int i = 0; i < 8; ++i)
                    s += __hip_atomic_load(&g_bar[2 * t][i << 5], __ATOMIC_RELAXED, __HIP_MEMORY_SCOPE_AGENT);
                if (s < NBLK) __builtin_amdgcn_s_sleep(2);
            } while (s < NBLK);
        }
        __syncthreads();

        // ---- P2: gh, 12 cols over h_hat, K=1024, coherent pipelined ----
        gemm12c(g_hhatT, wB, bhh_l, gh_l, red, tid);
        __syncthreads();

        // ---- gates + writeback (threads 0..255) ----
        if (tid < 256) {
            int cc = tid >> 6, b = tid & 63;
            float hh = hh_l[tid];
            float hr = gh_l[cc * 64 + b];
            float hz = gh_l[(4 + cc) * 64 + b];
            float hn = gh_l[(8 + cc) * 64 + b];
            float ir = gi_cur[cc * 64 + b];
            float iz = gi_cur[(4 + cc) * 64 + b];
            float in_ = gi_cur[(8 + cc) * 64 + b];
            float r = 1.f / (1.f + expf(-(ir + hr)));
            float u = 1.f / (1.f + expf(-(iz + hz)));
            float n = tanhf(in_ + r * hn);
            float v = (1.f - u) * n + u * hh;
            hn_l[tid] = v;
            int j = jb + cc;
            out[((size_t)b * S_ + t) * H_ + j] = v;
            if (t == S_ - 1)
                out[(size_t)B_ * S_ * H_ + (size_t)b * H_ + j] = v;
        }
        __syncthreads();
        if (tid < 128) {
            int c = tid >> 5, pb = (tid & 31) << 1;
            coh_store2(&g_hT[(t + 1) & 1][(jb + c) * 64 + pb], hn_l[(c << 6) + pb], hn_l[(c << 6) + pb + 1]);
        }
        __syncthreads();   // vmcnt(0) drain: h stores complete before arrive

        // ---- arrive B + wait B ----
        if (tid == 0) {
            __hip_atomic_fetch_add(&g_bar[2 * t + 1][barlane], 1u, __ATOMIC_RELAXED, __HIP_MEMORY_SCOPE_AGENT);
            unsigned s;
            do {
                s = 0;
                #pragma unroll
                for (int i = 0; i < 8; ++i)
                    s += __hip_atomic_load(&g_bar[2 * t + 1][i << 5], __ATOMIC_RELAXED, __HIP_MEMORY_SCOPE_AGENT);
                if (s < NBLK) __builtin_amdgcn_s_sleep(2);
            } while (s < NBLK);
        }
        __syncthreads();
    }
}

extern "C" void kernel_launch(void* const* d_in, const int* in_sizes, int n_in,
                              void* d_out, int out_size, void* d_ws, size_t ws_size,
                              hipStream_t stream) {
    const float* inputs = (const float*)d_in[0];
    const float* h0     = (const float*)d_in[1];
    const float* z      = (const float*)d_in[2];
    const float* Wlin   = (const float*)d_in[3];
    const float* blin   = (const float*)d_in[4];
    const float* Wih    = (const float*)d_in[5];
    const float* bih    = (const float*)d_in[6];
    const float* Whh    = (const float*)d_in[7];
    const float* bhh    = (const float*)d_in[8];
    float* out = (float*)d_out;

    hipLaunchKernelGGL(pre_transpose_x, dim3(S_ * 8), dim3(256), 0, stream, inputs);
    hipLaunchKernelGGL(pre_misc, dim3(H_), dim3(64), 0, stream, z, Wlin, blin, h0);
    hipLaunchKernelGGL(skipgru_2ph, dim3(NBLK), dim3(NTHR), 0, stream,
                       Wlin, Wih, bih, Whh, bhh, out);
}